// Round 7
// baseline (165.038 us; speedup 1.0000x reference)
//
#include <hip/hip_runtime.h>
#include <hip/hip_bf16.h>
#include <cstdint>
#include <cstddef>

// Problem constants (fixed by setup_inputs)
#define NB 8
#define LQ 5440
#define MROWS (NB * LQ)   // 43520

typedef __attribute__((ext_vector_type(8))) _Float16       f16x8;
typedef __attribute__((ext_vector_type(4))) float          f32x4;
typedef __attribute__((ext_vector_type(8))) unsigned short ushort8_t;

__device__ __forceinline__ unsigned short f2h(float f) {
    _Float16 h = (_Float16)f;           // RNE
    unsigned short u;
    __builtin_memcpy(&u, &h, 2);
    return u;
}
__device__ __forceinline__ float h2f(unsigned short u) {
    _Float16 h;
    __builtin_memcpy(&h, &u, 2);
    return (float)h;                    // fpext -> feeds v_fma_mix_f32
}

// ---------------------------------------------------------------------------
// Prep: fp16 conversions.
//   [0,65536)        WvT  (transposed Wv)  -> bigBt rows 0..255
//   [65536,131072)   Wv16n (native Wv)     -> operand for wcombo GEMM
//   [131072,229376)  WoaT ([Woff|Wattn]^T, 384 rows)
//   [229376,294912)  WoT  (transposed Wo)
// ---------------------------------------------------------------------------
__global__ __launch_bounds__(256) void prep_weights(
    const float* __restrict__ Wv, const float* __restrict__ Woff,
    const float* __restrict__ Wat, const float* __restrict__ Wo,
    unsigned short* __restrict__ bigBt,   // [640][256], rows 0..255 = WvT
    unsigned short* __restrict__ Wv16n,   // [256][256] native
    unsigned short* __restrict__ WoaT,    // [384][256]
    unsigned short* __restrict__ WoT)     // [256][256]
{
    const int id = blockIdx.x * 256 + threadIdx.x;
    if (id < 65536) {
        const int n = id >> 8, k = id & 255;
        bigBt[id] = f2h(Wv[k * 256 + n]);
    } else if (id < 131072) {
        const int p = id - 65536;
        Wv16n[p] = f2h(Wv[p]);
    } else if (id < 131072 + 98304) {
        const int p = id - 131072;
        const int n = p >> 8, k = p & 255;
        WoaT[p] = (n < 256) ? f2h(Woff[k * 256 + n])
                            : f2h(Wat[k * 128 + (n - 256)]);
    } else {
        const int p = id - (131072 + 98304);
        const int n = p >> 8, k = p & 255;
        WoT[p] = f2h(Wo[k * 256 + n]);
    }
}

// ---------------------------------------------------------------------------
// Combined bias:  fbias[0..255] = b_value;
//   fbias[256+n] = b_value . Woa[:,n] + {b_off|b_attn}[n]   (n = 0..383)
//   zb[0..383] = 0  (bias for the wcombo GEMM)
// block b<256: copy; 256<=b<640: 256-thread dot-reduce; b>=640: zeros.
// ---------------------------------------------------------------------------
__global__ __launch_bounds__(256) void combine_bias(
    const float* __restrict__ b_value, const float* __restrict__ Woff,
    const float* __restrict__ Wat, const float* __restrict__ b_off,
    const float* __restrict__ b_attn,
    float* __restrict__ fbias, float* __restrict__ zb)
{
    const int b = blockIdx.x;
    const int t = threadIdx.x;
    if (b < 256) {
        if (t == 0) fbias[b] = b_value[b];
        return;
    }
    if (b >= 640) {
        const int i = (b - 640) * 256 + t;
        if (i < 384) zb[i] = 0.f;
        return;
    }
    const int n = b - 256;
    float p = b_value[t] * ((n < 256) ? Woff[t * 256 + n]
                                      : Wat[t * 128 + (n - 256)]);
    // wave reduce
    for (int o = 32; o >= 1; o >>= 1) p += __shfl_xor(p, o);
    __shared__ float red[4];
    if ((t & 63) == 0) red[t >> 6] = p;
    __syncthreads();
    if (t == 0) {
        float s = red[0] + red[1] + red[2] + red[3];
        fbias[b] = s + ((n < 256) ? b_off[n] : b_attn[n - 256]);
    }
}

// ---------------------------------------------------------------------------
// fp16 MFMA GEMM (single/dual output) — unchanged structure from r5/r6.
// ---------------------------------------------------------------------------
#define LDT 40

template<bool A_FP32, bool F16_OUT>
__global__ __launch_bounds__(256) void gemm_mfma(
    const void* __restrict__ Ap, const unsigned short* __restrict__ Bt,
    const float* __restrict__ bias0, const float* __restrict__ bias1,
    void* __restrict__ C0, void* __restrict__ C1,
    int cs0, int cs1, int split)
{
    __shared__ unsigned short As[128 * LDT];
    __shared__ unsigned short Bs[128 * LDT];

    const int bm = blockIdx.y * 128;
    const int bn = blockIdx.x * 128;
    const int t    = threadIdx.x;
    const int lane = t & 63;
    const int wid  = t >> 6;
    const int wm   = (wid >> 1) * 64;
    const int wn   = (wid & 1) * 64;
    const int c    = lane & 15;
    const int qq   = lane >> 4;

    const int tr = t >> 1;
    const int kh = (t & 1) * 16;

    f32x4 acc[4][4];
#pragma unroll
    for (int i = 0; i < 4; ++i)
#pragma unroll
        for (int j = 0; j < 4; ++j)
            acc[i][j] = (f32x4){0.f, 0.f, 0.f, 0.f};

    for (int k0 = 0; k0 < 256; k0 += 32) {
        if (A_FP32) {
            const float4* Af = reinterpret_cast<const float4*>(
                (const float*)Ap + (size_t)(bm + tr) * 256 + k0 + kh);
            const float4 a0 = Af[0], a1 = Af[1], a2 = Af[2], a3 = Af[3];
            ushort8_t u0, u1;
            u0[0]=f2h(a0.x); u0[1]=f2h(a0.y); u0[2]=f2h(a0.z); u0[3]=f2h(a0.w);
            u0[4]=f2h(a1.x); u0[5]=f2h(a1.y); u0[6]=f2h(a1.z); u0[7]=f2h(a1.w);
            u1[0]=f2h(a2.x); u1[1]=f2h(a2.y); u1[2]=f2h(a2.z); u1[3]=f2h(a2.w);
            u1[4]=f2h(a3.x); u1[5]=f2h(a3.y); u1[6]=f2h(a3.z); u1[7]=f2h(a3.w);
            *reinterpret_cast<ushort8_t*>(&As[tr * LDT + kh])     = u0;
            *reinterpret_cast<ushort8_t*>(&As[tr * LDT + kh + 8]) = u1;
        } else {
            const ushort8_t* Ab = reinterpret_cast<const ushort8_t*>(
                (const unsigned short*)Ap + (size_t)(bm + tr) * 256 + k0 + kh);
            *reinterpret_cast<ushort8_t*>(&As[tr * LDT + kh])     = Ab[0];
            *reinterpret_cast<ushort8_t*>(&As[tr * LDT + kh + 8]) = Ab[1];
        }
        {
            const ushort8_t* Bb = reinterpret_cast<const ushort8_t*>(
                Bt + (size_t)(bn + tr) * 256 + k0 + kh);
            *reinterpret_cast<ushort8_t*>(&Bs[tr * LDT + kh])     = Bb[0];
            *reinterpret_cast<ushort8_t*>(&Bs[tr * LDT + kh + 8]) = Bb[1];
        }
        __syncthreads();

        f16x8 af[4], bfr[4];
#pragma unroll
        for (int i = 0; i < 4; ++i)
            af[i] = *reinterpret_cast<const f16x8*>(
                &As[(wm + i * 16 + c) * LDT + qq * 8]);
#pragma unroll
        for (int j = 0; j < 4; ++j)
            bfr[j] = *reinterpret_cast<const f16x8*>(
                &Bs[(wn + j * 16 + c) * LDT + qq * 8]);
#pragma unroll
        for (int i = 0; i < 4; ++i)
#pragma unroll
            for (int j = 0; j < 4; ++j)
                acc[i][j] = __builtin_amdgcn_mfma_f32_16x16x32_f16(
                    af[i], bfr[j], acc[i][j], 0, 0, 0);
        __syncthreads();
    }

#pragma unroll
    for (int j = 0; j < 4; ++j) {
        const int col    = bn + wn + j * 16 + c;
        const bool second = col >= split;
        const int ccol   = second ? col - split : col;
        const float bv   = second ? bias1[ccol] : bias0[ccol];
#pragma unroll
        for (int i = 0; i < 4; ++i) {
#pragma unroll
            for (int r = 0; r < 4; ++r) {
                const int row = bm + wm + i * 16 + qq * 4 + r;
                const float v0 = acc[i][j][r] + bv;
                if (F16_OUT) {
                    const float v1 = __shfl_xor(v0, 1);
                    if ((lane & 1) == 0) {
                        const unsigned int packed =
                            (unsigned int)f2h(v0) | ((unsigned int)f2h(v1) << 16);
                        unsigned short* Cb = (unsigned short*)(second ? C1 : C0);
                        const int cs = second ? cs1 : cs0;
                        *reinterpret_cast<unsigned int*>(
                            Cb + (size_t)row * cs + ccol) = packed;
                    }
                } else {
                    float* Cf = (float*)C0;
                    Cf[(size_t)row * cs0 + col] = v0;
                }
            }
        }
    }
}

// ---------------------------------------------------------------------------
// Fused front GEMM: [v | off | attn] = q(fp32) @ bigBt^T + fbias, N=640.
//   Same core as gemm_mfma<A_FP32=true>, 3-way split epilogue.
// ---------------------------------------------------------------------------
__global__ __launch_bounds__(256) void gemm_front(
    const float* __restrict__ Ap, const unsigned short* __restrict__ Bt,
    const float* __restrict__ fbias,
    unsigned short* __restrict__ v16, unsigned short* __restrict__ off16,
    unsigned short* __restrict__ at16)
{
    __shared__ unsigned short As[128 * LDT];
    __shared__ unsigned short Bs[128 * LDT];

    const int bm = blockIdx.y * 128;
    const int bn = blockIdx.x * 128;
    const int t    = threadIdx.x;
    const int lane = t & 63;
    const int wid  = t >> 6;
    const int wm   = (wid >> 1) * 64;
    const int wn   = (wid & 1) * 64;
    const int c    = lane & 15;
    const int qq   = lane >> 4;

    const int tr = t >> 1;
    const int kh = (t & 1) * 16;

    f32x4 acc[4][4];
#pragma unroll
    for (int i = 0; i < 4; ++i)
#pragma unroll
        for (int j = 0; j < 4; ++j)
            acc[i][j] = (f32x4){0.f, 0.f, 0.f, 0.f};

    for (int k0 = 0; k0 < 256; k0 += 32) {
        {
            const float4* Af = reinterpret_cast<const float4*>(
                Ap + (size_t)(bm + tr) * 256 + k0 + kh);
            const float4 a0 = Af[0], a1 = Af[1], a2 = Af[2], a3 = Af[3];
            ushort8_t u0, u1;
            u0[0]=f2h(a0.x); u0[1]=f2h(a0.y); u0[2]=f2h(a0.z); u0[3]=f2h(a0.w);
            u0[4]=f2h(a1.x); u0[5]=f2h(a1.y); u0[6]=f2h(a1.z); u0[7]=f2h(a1.w);
            u1[0]=f2h(a2.x); u1[1]=f2h(a2.y); u1[2]=f2h(a2.z); u1[3]=f2h(a2.w);
            u1[4]=f2h(a3.x); u1[5]=f2h(a3.y); u1[6]=f2h(a3.z); u1[7]=f2h(a3.w);
            *reinterpret_cast<ushort8_t*>(&As[tr * LDT + kh])     = u0;
            *reinterpret_cast<ushort8_t*>(&As[tr * LDT + kh + 8]) = u1;
        }
        {
            const ushort8_t* Bb = reinterpret_cast<const ushort8_t*>(
                Bt + (size_t)(bn + tr) * 256 + k0 + kh);
            *reinterpret_cast<ushort8_t*>(&Bs[tr * LDT + kh])     = Bb[0];
            *reinterpret_cast<ushort8_t*>(&Bs[tr * LDT + kh + 8]) = Bb[1];
        }
        __syncthreads();

        f16x8 af[4], bfr[4];
#pragma unroll
        for (int i = 0; i < 4; ++i)
            af[i] = *reinterpret_cast<const f16x8*>(
                &As[(wm + i * 16 + c) * LDT + qq * 8]);
#pragma unroll
        for (int j = 0; j < 4; ++j)
            bfr[j] = *reinterpret_cast<const f16x8*>(
                &Bs[(wn + j * 16 + c) * LDT + qq * 8]);
#pragma unroll
        for (int i = 0; i < 4; ++i)
#pragma unroll
            for (int j = 0; j < 4; ++j)
                acc[i][j] = __builtin_amdgcn_mfma_f32_16x16x32_f16(
                    af[i], bfr[j], acc[i][j], 0, 0, 0);
        __syncthreads();
    }

#pragma unroll
    for (int j = 0; j < 4; ++j) {
        const int col  = bn + wn + j * 16 + c;      // 0..639
        const float bv = fbias[col];
#pragma unroll
        for (int i = 0; i < 4; ++i) {
#pragma unroll
            for (int r = 0; r < 4; ++r) {
                const int row = bm + wm + i * 16 + qq * 4 + r;
                const float v0 = acc[i][j][r] + bv;
                const float v1 = __shfl_xor(v0, 1);
                if ((lane & 1) == 0) {
                    const unsigned int packed =
                        (unsigned int)f2h(v0) | ((unsigned int)f2h(v1) << 16);
                    unsigned short* dst;
                    if (col < 256)      dst = v16   + (size_t)row * 256 + col;
                    else if (col < 512) dst = off16 + (size_t)row * 256 + (col - 256);
                    else                dst = at16  + (size_t)row * 128 + (col - 512);
                    *reinterpret_cast<unsigned int*>(dst) = packed;
                }
            }
        }
    }
}

// ---------------------------------------------------------------------------
// Fused sampling: 16B gathers, skewed LDS (write-conflict-free), depth-2
// pipeline, XCD-swizzled blockIdx (one image per XCD -> v16 fits XCD L2).
//   LDS index (uint4 units): h*41 + 2j + (j>>1) + cp.
//   Writes (j=2k+pp): quad = (h + 5k + 2pp + cp) mod 8 -> 5k permutes each
//   8-lane group over all quads.  Reads: <=2-way (broadcast x4 cg lanes).
// ---------------------------------------------------------------------------
__global__ __launch_bounds__(256) void sample_kernel(
    const unsigned short* __restrict__ v16,     // [NB][LQ][256] fp16
    const unsigned short* __restrict__ off16,   // [NB][LQ][256] fp16
    const unsigned short* __restrict__ attn16,  // [NB][LQ][128] fp16
    const float* __restrict__ refpts,           // [NB][LQ][4][2] fp32
    unsigned short* __restrict__ pre16)         // [NB][LQ][256] fp16
{
    const int lane = threadIdx.x & 63;
    const int wv   = threadIdx.x >> 6;
    // XCD swizzle: 10880 blocks, 8 XCDs -> block (b%8)*1360 + b/8.
    // XCD x gets blocks [x*1360,(x+1)*1360) = rows [x*5440, ..) = image x.
    const int bid  = (blockIdx.x & 7) * 1360 + (blockIdx.x >> 3);
    const int row  = bid * 4 + wv;
    const int n    = row / LQ;

    __shared__ uint4 swi[4][328];   // [wave][h*41 + 2j + (j>>1) + cp]

    const ushort4 o4 = reinterpret_cast<const ushort4*>(off16)[(size_t)row * 64 + lane];
    const unsigned int lg = reinterpret_cast<const unsigned int*>(attn16)[(size_t)row * 64 + lane];
    const float l0 = h2f((unsigned short)(lg & 0xffff));
    const float l1 = h2f((unsigned short)(lg >> 16));

    const int h   = lane >> 3;
    const int k   = lane & 7;
    const int lev = k >> 1;
    const float rx = refpts[(size_t)row * 8 + lev * 2 + 0];
    const float ry = refpts[(size_t)row * 8 + lev * 2 + 1];

    // softmax across the head's 16 logits (8 lanes x 2)
    float m = fmaxf(l0, l1);
    m = fmaxf(m, __shfl_xor(m, 1));
    m = fmaxf(m, __shfl_xor(m, 2));
    m = fmaxf(m, __shfl_xor(m, 4));
    const float e0 = __expf(l0 - m);
    const float e1 = __expf(l1 - m);
    float s = e0 + e1;
    s += __shfl_xor(s, 1);
    s += __shfl_xor(s, 2);
    s += __shfl_xor(s, 4);
    const float inv = 1.f / s;

    const int  W     = 64 >> lev;
    const int  start = (lev == 0) ? 0 : (lev == 1) ? 4096 : (lev == 2) ? 5120 : 5376;
    const float rs   = 0.015625f * (float)(1 << lev);

#pragma unroll
    for (int pp = 0; pp < 2; ++pp) {
        const float lx = rx + h2f(pp ? o4.z : o4.x) * rs;
        const float ly = ry + h2f(pp ? o4.w : o4.y) * rs;
        const float wgt = (pp ? e1 : e0) * inv;

        const float x = lx * (float)W - 0.5f;
        const float y = ly * (float)W - 0.5f;
        const float fx = floorf(x), fy = floorf(y);
        const int xi = (int)fx, yi = (int)fy;
        const float wx = x - fx, wy = y - fy;

        const int x0 = min(max(xi, 0), W - 1);
        const int x1 = min(max(xi + 1, 0), W - 1);
        const int y0 = min(max(yi, 0), W - 1);
        const int y1 = min(max(yi + 1, 0), W - 1);
        const float vx0 = (xi >= 0 && xi < W)         ? (1.f - wx) : 0.f;
        const float vx1 = (xi + 1 >= 0 && xi + 1 < W) ? wx         : 0.f;
        const float vy0 = (yi >= 0 && yi < W)         ? (1.f - wy) : 0.f;
        const float vy1 = (yi + 1 >= 0 && yi + 1 < W) ? wy         : 0.f;

        const int hb  = h * 64;
        const unsigned int b00 = (unsigned int)((start + y0 * W + x0) * 512 + hb);
        const unsigned int b01 = (unsigned int)((start + y0 * W + x1) * 512 + hb);
        const unsigned int b10 = (unsigned int)((start + y1 * W + x0) * 512 + hb);
        const unsigned int b11 = (unsigned int)((start + y1 * W + x1) * 512 + hb);

        uint4 c0, c1;
        c0.x = __float_as_uint(wgt * vy0 * vx0);
        c0.y = __float_as_uint(wgt * vy0 * vx1);
        c0.z = b00; c0.w = b01;
        c1.x = __float_as_uint(wgt * vy1 * vx0);
        c1.y = __float_as_uint(wgt * vy1 * vx1);
        c1.z = b10; c1.w = b11;
        // idx = h*41 + 2*jj + (jj>>1) + cp, jj = 2k+pp -> h*41 + 5k + 2pp + cp
        const int base = h * 41 + 5 * k + 2 * pp;
        swi[wv][base + 0] = c0;
        swi[wv][base + 1] = c1;
    }
    __syncthreads();

    // ---- main gather loop ----
    const int cp = (lane >> 2) & 1;
    const int cg = lane & 3;
    const unsigned int koff = cg * 16;

    const int nu = __builtin_amdgcn_readfirstlane(n);
    const char* vn = reinterpret_cast<const char*>(v16) + (size_t)nu * (LQ * 512);
    const uint4* wib = &swi[wv][h * 41 + cp];

#define OFS(j) (2 * (j) + ((j) >> 1))
#define GLD(o) (*reinterpret_cast<const ushort8_t*>(vn + ((o) + koff)))

    float acc[8];
#pragma unroll
    for (int i = 0; i < 8; ++i) acc[i] = 0.f;

    uint4 wi0 = wib[OFS(0)];
    uint4 wi1 = wib[OFS(1)];
    uint4 wi2 = wib[OFS(2)];
    uint4 wi3 = wi2;
    ushort8_t va0 = GLD(wi0.z), vb0 = GLD(wi0.w);
    ushort8_t va1 = GLD(wi1.z), vb1 = GLD(wi1.w);
    ushort8_t va2 = va1,        vb2 = vb1;

#pragma unroll
    for (int j = 0; j < 16; ++j) {
        if (j <= 13) { va2 = GLD(wi2.z); vb2 = GLD(wi2.w); }
        if (j <= 12) wi3 = wib[OFS(j + 3)];

        const float wa = __uint_as_float(wi0.x);
        const float wb = __uint_as_float(wi0.y);
#pragma unroll
        for (int i = 0; i < 8; ++i)
            acc[i] = fmaf(h2f(va0[i]), wa, acc[i]);
#pragma unroll
        for (int i = 0; i < 8; ++i)
            acc[i] = fmaf(h2f(vb0[i]), wb, acc[i]);

        wi0 = wi1; wi1 = wi2; wi2 = wi3;
        va0 = va1; va1 = va2; vb0 = vb1; vb1 = vb2;
    }
#undef OFS
#undef GLD

    // combine corner-pair partials (lane ^ 4 flips cp)
#pragma unroll
    for (int i = 0; i < 8; ++i)
        acc[i] += __shfl_xor(acc[i], 4);

    if (cp == 0) {
        ushort8_t st;
#pragma unroll
        for (int i = 0; i < 8; ++i) st[i] = f2h(acc[i]);
        *reinterpret_cast<ushort8_t*>(
            pre16 + (size_t)row * 256 + h * 32 + cg * 8) = st;
    }
}

// ---------------------------------------------------------------------------
extern "C" void kernel_launch(void* const* d_in, const int* in_sizes, int n_in,
                              void* d_out, int out_size, void* d_ws, size_t ws_size,
                              hipStream_t stream)
{
    const float* query   = (const float*)d_in[0];
    const float* refpts  = (const float*)d_in[1];
    const float* W_value = (const float*)d_in[4];
    const float* b_value = (const float*)d_in[5];
    const float* W_off   = (const float*)d_in[6];
    const float* b_off   = (const float*)d_in[7];
    const float* W_attn  = (const float*)d_in[8];
    const float* b_attn  = (const float*)d_in[9];
    const float* W_out   = (const float*)d_in[10];
    const float* b_out   = (const float*)d_in[11];
    float* out = (float*)d_out;

    // Workspace layout (fp16 unless noted)
    unsigned short* ws_v16   = (unsigned short*)d_ws;                  // 43520*256
    unsigned short* ws_off16 = ws_v16   + (size_t)MROWS * 256;         // 43520*256
    unsigned short* ws_at16  = ws_off16 + (size_t)MROWS * 256;         // 43520*128
    unsigned short* ws_pre16 = ws_at16  + (size_t)MROWS * 128;         // 43520*256
    unsigned short* ws_bigBt = ws_pre16 + (size_t)MROWS * 256;         // 640*256
    unsigned short* ws_wv16n = ws_bigBt + 640 * 256;                   // 256*256
    unsigned short* ws_woaT  = ws_wv16n + 65536;                       // 384*256
    unsigned short* ws_woT   = ws_woaT  + 98304;                       // 256*256
    float*          ws_fbias = (float*)(ws_woT + 65536);               // 640 f32
    float*          ws_zb    = ws_fbias + 640;                         // 384 f32

    // 1) fp16 weight conversions (WvT -> bigBt rows 0..255)
    prep_weights<<<dim3(1152), 256, 0, stream>>>(
        W_value, W_off, W_attn, W_out, ws_bigBt, ws_wv16n, ws_woaT, ws_woT);

    // 2) combined bias + zero bias
    combine_bias<<<dim3(642), 256, 0, stream>>>(
        b_value, W_off, W_attn, b_off, b_attn, ws_fbias, ws_zb);

    // 3) WcT = WoaT @ Wv   ([384][256] fp16) -> bigBt rows 256..639
    gemm_mfma<false, true><<<dim3(2, 3), 256, 0, stream>>>(
        ws_woaT, ws_wv16n, ws_zb, ws_zb,
        ws_bigBt + 65536, ws_bigBt + 65536, 256, 256, 1 << 30);

    // 4) fused front GEMM: [v|off|attn] = q @ bigBt^T + fbias
    gemm_front<<<dim3(5, 340), 256, 0, stream>>>(
        query, ws_bigBt, ws_fbias, ws_v16, ws_off16, ws_at16);

    // 5) fused softmax + bilinear sampling -> pre16
    sample_kernel<<<dim3(MROWS / 4), 256, 0, stream>>>(
        ws_v16, ws_off16, ws_at16, refpts, ws_pre16);

    // 6) out = pre @ W_out + b_out (fp32)
    gemm_mfma<false, false><<<dim3(2, 340), 256, 0, stream>>>(
        ws_pre16, ws_woT, b_out, b_out, out, out, 256, 256, 1 << 30);
}

// Round 8
// 146.139 us; speedup vs baseline: 1.1293x; 1.1293x over previous
//
#include <hip/hip_runtime.h>
#include <hip/hip_bf16.h>
#include <cstdint>
#include <cstddef>

// Problem constants (fixed by setup_inputs)
#define NB 8
#define LQ 5440
#define MROWS (NB * LQ)   // 43520

typedef __attribute__((ext_vector_type(8))) _Float16       f16x8;
typedef __attribute__((ext_vector_type(4))) float          f32x4;
typedef __attribute__((ext_vector_type(8))) unsigned short ushort8_t;

__device__ __forceinline__ unsigned short f2h(float f) {
    _Float16 h = (_Float16)f;           // RNE
    unsigned short u;
    __builtin_memcpy(&u, &h, 2);
    return u;
}
__device__ __forceinline__ float h2f(unsigned short u) {
    _Float16 h;
    __builtin_memcpy(&h, &u, 2);
    return (float)h;                    // fpext -> feeds v_fma_mix_f32
}

// Bijective XCD swizzle (m204 formula) + column-inner tile order.
// Dispatch order is x-fastest; XCD = dispatch_id % 8. Remap so each XCD
// owns a contiguous chunk of linear ids; bx = new % nx keeps all column
// tiles of one A row-panel adjacent (same XCD -> A panel L2-hits).
__device__ __forceinline__ void xcd_tile(int& bx, int& by) {
    const int nx   = gridDim.x;
    const int nwg  = nx * gridDim.y;
    const int orig = blockIdx.y * nx + blockIdx.x;
    const int q = nwg >> 3, r = nwg & 7;
    const int xcd = orig & 7, pos = orig >> 3;
    const int nw = (xcd < r ? xcd * (q + 1) : r * (q + 1) + (xcd - r) * q) + pos;
    bx = nw % nx;
    by = nw / nx;
}

// ---------------------------------------------------------------------------
// Prep: fp16 conversions.
// ---------------------------------------------------------------------------
__global__ __launch_bounds__(256) void prep_weights(
    const float* __restrict__ Wv, const float* __restrict__ Woff,
    const float* __restrict__ Wat, const float* __restrict__ Wo,
    unsigned short* __restrict__ bigBt,   // [640][256], rows 0..255 = WvT
    unsigned short* __restrict__ Wv16n,   // [256][256] native
    unsigned short* __restrict__ WoaT,    // [384][256]
    unsigned short* __restrict__ WoT)     // [256][256]
{
    const int id = blockIdx.x * 256 + threadIdx.x;
    if (id < 65536) {
        const int n = id >> 8, k = id & 255;
        bigBt[id] = f2h(Wv[k * 256 + n]);
    } else if (id < 131072) {
        const int p = id - 65536;
        Wv16n[p] = f2h(Wv[p]);
    } else if (id < 131072 + 98304) {
        const int p = id - 131072;
        const int n = p >> 8, k = p & 255;
        WoaT[p] = (n < 256) ? f2h(Woff[k * 256 + n])
                            : f2h(Wat[k * 128 + (n - 256)]);
    } else {
        const int p = id - (131072 + 98304);
        const int n = p >> 8, k = p & 255;
        WoT[p] = f2h(Wo[k * 256 + n]);
    }
}

// ---------------------------------------------------------------------------
// Combined bias:  fbias[0..255] = b_value;
//   fbias[256+n] = b_value . Woa[:,n] + {b_off|b_attn}[n]   (n = 0..383)
//   zb[0..383] = 0
// ---------------------------------------------------------------------------
__global__ __launch_bounds__(256) void combine_bias(
    const float* __restrict__ b_value, const float* __restrict__ Woff,
    const float* __restrict__ Wat, const float* __restrict__ b_off,
    const float* __restrict__ b_attn,
    float* __restrict__ fbias, float* __restrict__ zb)
{
    const int b = blockIdx.x;
    const int t = threadIdx.x;
    if (b < 256) {
        if (t == 0) fbias[b] = b_value[b];
        return;
    }
    if (b >= 640) {
        const int i = (b - 640) * 256 + t;
        if (i < 384) zb[i] = 0.f;
        return;
    }
    const int n = b - 256;
    float p = b_value[t] * ((n < 256) ? Woff[t * 256 + n]
                                      : Wat[t * 128 + (n - 256)]);
    for (int o = 32; o >= 1; o >>= 1) p += __shfl_xor(p, o);
    __shared__ float red[4];
    if ((t & 63) == 0) red[t >> 6] = p;
    __syncthreads();
    if (t == 0) {
        float s = red[0] + red[1] + red[2] + red[3];
        fbias[b] = s + ((n < 256) ? b_off[n] : b_attn[n - 256]);
    }
}

// ---------------------------------------------------------------------------
// fp16 MFMA GEMM (single/dual output), now XCD-swizzled tile mapping.
// ---------------------------------------------------------------------------
#define LDT 40

template<bool A_FP32, bool F16_OUT>
__global__ __launch_bounds__(256) void gemm_mfma(
    const void* __restrict__ Ap, const unsigned short* __restrict__ Bt,
    const float* __restrict__ bias0, const float* __restrict__ bias1,
    void* __restrict__ C0, void* __restrict__ C1,
    int cs0, int cs1, int split)
{
    __shared__ unsigned short As[128 * LDT];
    __shared__ unsigned short Bs[128 * LDT];

    int bxi, byi;
    xcd_tile(bxi, byi);
    const int bm = byi * 128;
    const int bn = bxi * 128;
    const int t    = threadIdx.x;
    const int lane = t & 63;
    const int wid  = t >> 6;
    const int wm   = (wid >> 1) * 64;
    const int wn   = (wid & 1) * 64;
    const int c    = lane & 15;
    const int qq   = lane >> 4;

    const int tr = t >> 1;
    const int kh = (t & 1) * 16;

    f32x4 acc[4][4];
#pragma unroll
    for (int i = 0; i < 4; ++i)
#pragma unroll
        for (int j = 0; j < 4; ++j)
            acc[i][j] = (f32x4){0.f, 0.f, 0.f, 0.f};

    for (int k0 = 0; k0 < 256; k0 += 32) {
        if (A_FP32) {
            const float4* Af = reinterpret_cast<const float4*>(
                (const float*)Ap + (size_t)(bm + tr) * 256 + k0 + kh);
            const float4 a0 = Af[0], a1 = Af[1], a2 = Af[2], a3 = Af[3];
            ushort8_t u0, u1;
            u0[0]=f2h(a0.x); u0[1]=f2h(a0.y); u0[2]=f2h(a0.z); u0[3]=f2h(a0.w);
            u0[4]=f2h(a1.x); u0[5]=f2h(a1.y); u0[6]=f2h(a1.z); u0[7]=f2h(a1.w);
            u1[0]=f2h(a2.x); u1[1]=f2h(a2.y); u1[2]=f2h(a2.z); u1[3]=f2h(a2.w);
            u1[4]=f2h(a3.x); u1[5]=f2h(a3.y); u1[6]=f2h(a3.z); u1[7]=f2h(a3.w);
            *reinterpret_cast<ushort8_t*>(&As[tr * LDT + kh])     = u0;
            *reinterpret_cast<ushort8_t*>(&As[tr * LDT + kh + 8]) = u1;
        } else {
            const ushort8_t* Ab = reinterpret_cast<const ushort8_t*>(
                (const unsigned short*)Ap + (size_t)(bm + tr) * 256 + k0 + kh);
            *reinterpret_cast<ushort8_t*>(&As[tr * LDT + kh])     = Ab[0];
            *reinterpret_cast<ushort8_t*>(&As[tr * LDT + kh + 8]) = Ab[1];
        }
        {
            const ushort8_t* Bb = reinterpret_cast<const ushort8_t*>(
                Bt + (size_t)(bn + tr) * 256 + k0 + kh);
            *reinterpret_cast<ushort8_t*>(&Bs[tr * LDT + kh])     = Bb[0];
            *reinterpret_cast<ushort8_t*>(&Bs[tr * LDT + kh + 8]) = Bb[1];
        }
        __syncthreads();

        f16x8 af[4], bfr[4];
#pragma unroll
        for (int i = 0; i < 4; ++i)
            af[i] = *reinterpret_cast<const f16x8*>(
                &As[(wm + i * 16 + c) * LDT + qq * 8]);
#pragma unroll
        for (int j = 0; j < 4; ++j)
            bfr[j] = *reinterpret_cast<const f16x8*>(
                &Bs[(wn + j * 16 + c) * LDT + qq * 8]);
#pragma unroll
        for (int i = 0; i < 4; ++i)
#pragma unroll
            for (int j = 0; j < 4; ++j)
                acc[i][j] = __builtin_amdgcn_mfma_f32_16x16x32_f16(
                    af[i], bfr[j], acc[i][j], 0, 0, 0);
        __syncthreads();
    }

#pragma unroll
    for (int j = 0; j < 4; ++j) {
        const int col    = bn + wn + j * 16 + c;
        const bool second = col >= split;
        const int ccol   = second ? col - split : col;
        const float bv   = second ? bias1[ccol] : bias0[ccol];
#pragma unroll
        for (int i = 0; i < 4; ++i) {
#pragma unroll
            for (int r = 0; r < 4; ++r) {
                const int row = bm + wm + i * 16 + qq * 4 + r;
                const float v0 = acc[i][j][r] + bv;
                if (F16_OUT) {
                    const float v1 = __shfl_xor(v0, 1);
                    if ((lane & 1) == 0) {
                        const unsigned int packed =
                            (unsigned int)f2h(v0) | ((unsigned int)f2h(v1) << 16);
                        unsigned short* Cb = (unsigned short*)(second ? C1 : C0);
                        const int cs = second ? cs1 : cs0;
                        *reinterpret_cast<unsigned int*>(
                            Cb + (size_t)row * cs + ccol) = packed;
                    }
                } else {
                    float* Cf = (float*)C0;
                    Cf[(size_t)row * cs0 + col] = v0;
                }
            }
        }
    }
}

// ---------------------------------------------------------------------------
// Fused front GEMM: [v | off | attn] = q(fp32) @ bigBt^T + fbias, N=640.
//   XCD-swizzled, column-inner: all 5 col-tiles of a row-panel on one XCD.
// ---------------------------------------------------------------------------
__global__ __launch_bounds__(256) void gemm_front(
    const float* __restrict__ Ap, const unsigned short* __restrict__ Bt,
    const float* __restrict__ fbias,
    unsigned short* __restrict__ v16, unsigned short* __restrict__ off16,
    unsigned short* __restrict__ at16)
{
    __shared__ unsigned short As[128 * LDT];
    __shared__ unsigned short Bs[128 * LDT];

    int bxi, byi;
    xcd_tile(bxi, byi);
    const int bm = byi * 128;
    const int bn = bxi * 128;
    const int t    = threadIdx.x;
    const int lane = t & 63;
    const int wid  = t >> 6;
    const int wm   = (wid >> 1) * 64;
    const int wn   = (wid & 1) * 64;
    const int c    = lane & 15;
    const int qq   = lane >> 4;

    const int tr = t >> 1;
    const int kh = (t & 1) * 16;

    f32x4 acc[4][4];
#pragma unroll
    for (int i = 0; i < 4; ++i)
#pragma unroll
        for (int j = 0; j < 4; ++j)
            acc[i][j] = (f32x4){0.f, 0.f, 0.f, 0.f};

    for (int k0 = 0; k0 < 256; k0 += 32) {
        {
            const float4* Af = reinterpret_cast<const float4*>(
                Ap + (size_t)(bm + tr) * 256 + k0 + kh);
            const float4 a0 = Af[0], a1 = Af[1], a2 = Af[2], a3 = Af[3];
            ushort8_t u0, u1;
            u0[0]=f2h(a0.x); u0[1]=f2h(a0.y); u0[2]=f2h(a0.z); u0[3]=f2h(a0.w);
            u0[4]=f2h(a1.x); u0[5]=f2h(a1.y); u0[6]=f2h(a1.z); u0[7]=f2h(a1.w);
            u1[0]=f2h(a2.x); u1[1]=f2h(a2.y); u1[2]=f2h(a2.z); u1[3]=f2h(a2.w);
            u1[4]=f2h(a3.x); u1[5]=f2h(a3.y); u1[6]=f2h(a3.z); u1[7]=f2h(a3.w);
            *reinterpret_cast<ushort8_t*>(&As[tr * LDT + kh])     = u0;
            *reinterpret_cast<ushort8_t*>(&As[tr * LDT + kh + 8]) = u1;
        }
        {
            const ushort8_t* Bb = reinterpret_cast<const ushort8_t*>(
                Bt + (size_t)(bn + tr) * 256 + k0 + kh);
            *reinterpret_cast<ushort8_t*>(&Bs[tr * LDT + kh])     = Bb[0];
            *reinterpret_cast<ushort8_t*>(&Bs[tr * LDT + kh + 8]) = Bb[1];
        }
        __syncthreads();

        f16x8 af[4], bfr[4];
#pragma unroll
        for (int i = 0; i < 4; ++i)
            af[i] = *reinterpret_cast<const f16x8*>(
                &As[(wm + i * 16 + c) * LDT + qq * 8]);
#pragma unroll
        for (int j = 0; j < 4; ++j)
            bfr[j] = *reinterpret_cast<const f16x8*>(
                &Bs[(wn + j * 16 + c) * LDT + qq * 8]);
#pragma unroll
        for (int i = 0; i < 4; ++i)
#pragma unroll
            for (int j = 0; j < 4; ++j)
                acc[i][j] = __builtin_amdgcn_mfma_f32_16x16x32_f16(
                    af[i], bfr[j], acc[i][j], 0, 0, 0);
        __syncthreads();
    }

#pragma unroll
    for (int j = 0; j < 4; ++j) {
        const int col  = bn + wn + j * 16 + c;      // 0..639
        const float bv = fbias[col];
#pragma unroll
        for (int i = 0; i < 4; ++i) {
#pragma unroll
            for (int r = 0; r < 4; ++r) {
                const int row = bm + wm + i * 16 + qq * 4 + r;
                const float v0 = acc[i][j][r] + bv;
                const float v1 = __shfl_xor(v0, 1);
                if ((lane & 1) == 0) {
                    const unsigned int packed =
                        (unsigned int)f2h(v0) | ((unsigned int)f2h(v1) << 16);
                    unsigned short* dst;
                    if (col < 256)      dst = v16   + (size_t)row * 256 + col;
                    else if (col < 512) dst = off16 + (size_t)row * 256 + (col - 256);
                    else                dst = at16  + (size_t)row * 128 + (col - 512);
                    *reinterpret_cast<unsigned int*>(dst) = packed;
                }
            }
        }
    }
}

// ---------------------------------------------------------------------------
// Fused sampling: 16B gathers, skewed LDS, depth-2 pipeline, XCD-swizzled
// (one image per XCD -> v16 image fits XCD L2).  Unchanged from round 7.
// ---------------------------------------------------------------------------
__global__ __launch_bounds__(256) void sample_kernel(
    const unsigned short* __restrict__ v16,     // [NB][LQ][256] fp16
    const unsigned short* __restrict__ off16,   // [NB][LQ][256] fp16
    const unsigned short* __restrict__ attn16,  // [NB][LQ][128] fp16
    const float* __restrict__ refpts,           // [NB][LQ][4][2] fp32
    unsigned short* __restrict__ pre16)         // [NB][LQ][256] fp16
{
    const int lane = threadIdx.x & 63;
    const int wv   = threadIdx.x >> 6;
    const int bid  = (blockIdx.x & 7) * 1360 + (blockIdx.x >> 3);
    const int row  = bid * 4 + wv;
    const int n    = row / LQ;

    __shared__ uint4 swi[4][328];   // [wave][h*41 + 2j + (j>>1) + cp]

    const ushort4 o4 = reinterpret_cast<const ushort4*>(off16)[(size_t)row * 64 + lane];
    const unsigned int lg = reinterpret_cast<const unsigned int*>(attn16)[(size_t)row * 64 + lane];
    const float l0 = h2f((unsigned short)(lg & 0xffff));
    const float l1 = h2f((unsigned short)(lg >> 16));

    const int h   = lane >> 3;
    const int k   = lane & 7;
    const int lev = k >> 1;
    const float rx = refpts[(size_t)row * 8 + lev * 2 + 0];
    const float ry = refpts[(size_t)row * 8 + lev * 2 + 1];

    float m = fmaxf(l0, l1);
    m = fmaxf(m, __shfl_xor(m, 1));
    m = fmaxf(m, __shfl_xor(m, 2));
    m = fmaxf(m, __shfl_xor(m, 4));
    const float e0 = __expf(l0 - m);
    const float e1 = __expf(l1 - m);
    float s = e0 + e1;
    s += __shfl_xor(s, 1);
    s += __shfl_xor(s, 2);
    s += __shfl_xor(s, 4);
    const float inv = 1.f / s;

    const int  W     = 64 >> lev;
    const int  start = (lev == 0) ? 0 : (lev == 1) ? 4096 : (lev == 2) ? 5120 : 5376;
    const float rs   = 0.015625f * (float)(1 << lev);

#pragma unroll
    for (int pp = 0; pp < 2; ++pp) {
        const float lx = rx + h2f(pp ? o4.z : o4.x) * rs;
        const float ly = ry + h2f(pp ? o4.w : o4.y) * rs;
        const float wgt = (pp ? e1 : e0) * inv;

        const float x = lx * (float)W - 0.5f;
        const float y = ly * (float)W - 0.5f;
        const float fx = floorf(x), fy = floorf(y);
        const int xi = (int)fx, yi = (int)fy;
        const float wx = x - fx, wy = y - fy;

        const int x0 = min(max(xi, 0), W - 1);
        const int x1 = min(max(xi + 1, 0), W - 1);
        const int y0 = min(max(yi, 0), W - 1);
        const int y1 = min(max(yi + 1, 0), W - 1);
        const float vx0 = (xi >= 0 && xi < W)         ? (1.f - wx) : 0.f;
        const float vx1 = (xi + 1 >= 0 && xi + 1 < W) ? wx         : 0.f;
        const float vy0 = (yi >= 0 && yi < W)         ? (1.f - wy) : 0.f;
        const float vy1 = (yi + 1 >= 0 && yi + 1 < W) ? wy         : 0.f;

        const int hb  = h * 64;
        const unsigned int b00 = (unsigned int)((start + y0 * W + x0) * 512 + hb);
        const unsigned int b01 = (unsigned int)((start + y0 * W + x1) * 512 + hb);
        const unsigned int b10 = (unsigned int)((start + y1 * W + x0) * 512 + hb);
        const unsigned int b11 = (unsigned int)((start + y1 * W + x1) * 512 + hb);

        uint4 c0, c1;
        c0.x = __float_as_uint(wgt * vy0 * vx0);
        c0.y = __float_as_uint(wgt * vy0 * vx1);
        c0.z = b00; c0.w = b01;
        c1.x = __float_as_uint(wgt * vy1 * vx0);
        c1.y = __float_as_uint(wgt * vy1 * vx1);
        c1.z = b10; c1.w = b11;
        const int base = h * 41 + 5 * k + 2 * pp;
        swi[wv][base + 0] = c0;
        swi[wv][base + 1] = c1;
    }
    __syncthreads();

    const int cp = (lane >> 2) & 1;
    const int cg = lane & 3;
    const unsigned int koff = cg * 16;

    const int nu = __builtin_amdgcn_readfirstlane(n);
    const char* vn = reinterpret_cast<const char*>(v16) + (size_t)nu * (LQ * 512);
    const uint4* wib = &swi[wv][h * 41 + cp];

#define OFS(j) (2 * (j) + ((j) >> 1))
#define GLD(o) (*reinterpret_cast<const ushort8_t*>(vn + ((o) + koff)))

    float acc[8];
#pragma unroll
    for (int i = 0; i < 8; ++i) acc[i] = 0.f;

    uint4 wi0 = wib[OFS(0)];
    uint4 wi1 = wib[OFS(1)];
    uint4 wi2 = wib[OFS(2)];
    uint4 wi3 = wi2;
    ushort8_t va0 = GLD(wi0.z), vb0 = GLD(wi0.w);
    ushort8_t va1 = GLD(wi1.z), vb1 = GLD(wi1.w);
    ushort8_t va2 = va1,        vb2 = vb1;

#pragma unroll
    for (int j = 0; j < 16; ++j) {
        if (j <= 13) { va2 = GLD(wi2.z); vb2 = GLD(wi2.w); }
        if (j <= 12) wi3 = wib[OFS(j + 3)];

        const float wa = __uint_as_float(wi0.x);
        const float wb = __uint_as_float(wi0.y);
#pragma unroll
        for (int i = 0; i < 8; ++i)
            acc[i] = fmaf(h2f(va0[i]), wa, acc[i]);
#pragma unroll
        for (int i = 0; i < 8; ++i)
            acc[i] = fmaf(h2f(vb0[i]), wb, acc[i]);

        wi0 = wi1; wi1 = wi2; wi2 = wi3;
        va0 = va1; va1 = va2; vb0 = vb1; vb1 = vb2;
    }
#undef OFS
#undef GLD

#pragma unroll
    for (int i = 0; i < 8; ++i)
        acc[i] += __shfl_xor(acc[i], 4);

    if (cp == 0) {
        ushort8_t st;
#pragma unroll
        for (int i = 0; i < 8; ++i) st[i] = f2h(acc[i]);
        *reinterpret_cast<ushort8_t*>(
            pre16 + (size_t)row * 256 + h * 32 + cg * 8) = st;
    }
}

// ---------------------------------------------------------------------------
extern "C" void kernel_launch(void* const* d_in, const int* in_sizes, int n_in,
                              void* d_out, int out_size, void* d_ws, size_t ws_size,
                              hipStream_t stream)
{
    const float* query   = (const float*)d_in[0];
    const float* refpts  = (const float*)d_in[1];
    const float* W_value = (const float*)d_in[4];
    const float* b_value = (const float*)d_in[5];
    const float* W_off   = (const float*)d_in[6];
    const float* b_off   = (const float*)d_in[7];
    const float* W_attn  = (const float*)d_in[8];
    const float* b_attn  = (const float*)d_in[9];
    const float* W_out   = (const float*)d_in[10];
    const float* b_out   = (const float*)d_in[11];
    float* out = (float*)d_out;

    // Workspace layout (fp16 unless noted)
    unsigned short* ws_v16   = (unsigned short*)d_ws;                  // 43520*256
    unsigned short* ws_off16 = ws_v16   + (size_t)MROWS * 256;         // 43520*256
    unsigned short* ws_at16  = ws_off16 + (size_t)MROWS * 256;         // 43520*128
    unsigned short* ws_pre16 = ws_at16  + (size_t)MROWS * 128;         // 43520*256
    unsigned short* ws_bigBt = ws_pre16 + (size_t)MROWS * 256;         // 640*256
    unsigned short* ws_wv16n = ws_bigBt + 640 * 256;                   // 256*256
    unsigned short* ws_woaT  = ws_wv16n + 65536;                       // 384*256
    unsigned short* ws_woT   = ws_woaT  + 98304;                       // 256*256
    float*          ws_fbias = (float*)(ws_woT + 65536);               // 640 f32
    float*          ws_zb    = ws_fbias + 640;                         // 384 f32

    prep_weights<<<dim3(1152), 256, 0, stream>>>(
        W_value, W_off, W_attn, W_out, ws_bigBt, ws_wv16n, ws_woaT, ws_woT);

    combine_bias<<<dim3(642), 256, 0, stream>>>(
        b_value, W_off, W_attn, b_off, b_attn, ws_fbias, ws_zb);

    // WcT = WoaT @ Wv -> bigBt rows 256..639
    gemm_mfma<false, true><<<dim3(2, 3), 256, 0, stream>>>(
        ws_woaT, ws_wv16n, ws_zb, ws_zb,
        ws_bigBt + 65536, ws_bigBt + 65536, 256, 256, 1 << 30);

    // fused front GEMM: [v|off|attn] = q @ bigBt^T + fbias
    gemm_front<<<dim3(5, 340), 256, 0, stream>>>(
        query, ws_bigBt, ws_fbias, ws_v16, ws_off16, ws_at16);

    // fused softmax + bilinear sampling -> pre16
    sample_kernel<<<dim3(MROWS / 4), 256, 0, stream>>>(
        ws_v16, ws_off16, ws_at16, refpts, ws_pre16);

    // out = pre @ W_out + b_out (fp32)
    gemm_mfma<false, false><<<dim3(2, 340), 256, 0, stream>>>(
        ws_pre16, ws_woT, b_out, b_out, out, out, 256, 256, 1 << 30);
}

// Round 9
// 138.003 us; speedup vs baseline: 1.1959x; 1.0590x over previous
//
#include <hip/hip_runtime.h>
#include <hip/hip_bf16.h>
#include <cstdint>
#include <cstddef>

// Problem constants (fixed by setup_inputs)
#define NB 8
#define LQ 5440
#define MROWS (NB * LQ)   // 43520

typedef __attribute__((ext_vector_type(8))) _Float16       f16x8;
typedef __attribute__((ext_vector_type(4))) float          f32x4;
typedef __attribute__((ext_vector_type(8))) unsigned short ushort8_t;

__device__ __forceinline__ unsigned short f2h(float f) {
    _Float16 h = (_Float16)f;           // RNE
    unsigned short u;
    __builtin_memcpy(&u, &h, 2);
    return u;
}
__device__ __forceinline__ float h2f(unsigned short u) {
    _Float16 h;
    __builtin_memcpy(&h, &u, 2);
    return (float)h;                    // fpext -> feeds v_fma_mix_f32
}

// Bijective XCD swizzle (m204) + column-inner tile order.
__device__ __forceinline__ void xcd_tile(int& bx, int& by) {
    const int nx   = gridDim.x;
    const int nwg  = nx * gridDim.y;
    const int orig = blockIdx.y * nx + blockIdx.x;
    const int q = nwg >> 3, r = nwg & 7;
    const int xcd = orig & 7, pos = orig >> 3;
    const int nw = (xcd < r ? xcd * (q + 1) : r * (q + 1) + (xcd - r) * q) + pos;
    bx = nw % nx;
    by = nw / nx;
}

// ---------------------------------------------------------------------------
// Prep: fp16 conversions.
// ---------------------------------------------------------------------------
__global__ __launch_bounds__(256) void prep_weights(
    const float* __restrict__ Wv, const float* __restrict__ Woff,
    const float* __restrict__ Wat, const float* __restrict__ Wo,
    unsigned short* __restrict__ bigBt,   // [640][256], rows 0..255 = WvT
    unsigned short* __restrict__ Wv16n,   // [256][256] native
    unsigned short* __restrict__ WoaT,    // [384][256]
    unsigned short* __restrict__ WoT)     // [256][256]
{
    const int id = blockIdx.x * 256 + threadIdx.x;
    if (id < 65536) {
        const int n = id >> 8, k = id & 255;
        bigBt[id] = f2h(Wv[k * 256 + n]);
    } else if (id < 131072) {
        const int p = id - 65536;
        Wv16n[p] = f2h(Wv[p]);
    } else if (id < 131072 + 98304) {
        const int p = id - 131072;
        const int n = p >> 8, k = p & 255;
        WoaT[p] = (n < 256) ? f2h(Woff[k * 256 + n])
                            : f2h(Wat[k * 128 + (n - 256)]);
    } else {
        const int p = id - (131072 + 98304);
        const int n = p >> 8, k = p & 255;
        WoT[p] = f2h(Wo[k * 256 + n]);
    }
}

// ---------------------------------------------------------------------------
// Combined bias:  fbias[0..255] = b_value;
//   fbias[256+n] = b_value . Woa[:,n] + {b_off|b_attn}[n];  zb = 0
// ---------------------------------------------------------------------------
__global__ __launch_bounds__(256) void combine_bias(
    const float* __restrict__ b_value, const float* __restrict__ Woff,
    const float* __restrict__ Wat, const float* __restrict__ b_off,
    const float* __restrict__ b_attn,
    float* __restrict__ fbias, float* __restrict__ zb)
{
    const int b = blockIdx.x;
    const int t = threadIdx.x;
    if (b < 256) {
        if (t == 0) fbias[b] = b_value[b];
        return;
    }
    if (b >= 640) {
        const int i = (b - 640) * 256 + t;
        if (i < 384) zb[i] = 0.f;
        return;
    }
    const int n = b - 256;
    float p = b_value[t] * ((n < 256) ? Woff[t * 256 + n]
                                      : Wat[t * 128 + (n - 256)]);
    for (int o = 32; o >= 1; o >>= 1) p += __shfl_xor(p, o);
    __shared__ float red[4];
    if ((t & 63) == 0) red[t >> 6] = p;
    __syncthreads();
    if (t == 0) {
        float s = red[0] + red[1] + red[2] + red[3];
        fbias[b] = s + ((n < 256) ? b_off[n] : b_attn[n - 256]);
    }
}

// ---------------------------------------------------------------------------
// fp16 MFMA GEMM with 2-phase prefetch (T14/T3-minimum):
//   issue k+1 global loads into regs BEFORE computing k from LDS; vmcnt
//   drain happens at the post-barrier LDS write, hidden under compute.
// ---------------------------------------------------------------------------
#define LDT 40

template<bool A_FP32, bool F16_OUT>
__global__ __launch_bounds__(256) void gemm_mfma(
    const void* __restrict__ Ap, const unsigned short* __restrict__ Bt,
    const float* __restrict__ bias0, const float* __restrict__ bias1,
    void* __restrict__ C0, void* __restrict__ C1,
    int cs0, int cs1, int split)
{
    __shared__ unsigned short As[128 * LDT];
    __shared__ unsigned short Bs[128 * LDT];

    int bxi, byi;
    xcd_tile(bxi, byi);
    const int bm = byi * 128;
    const int bn = bxi * 128;
    const int t    = threadIdx.x;
    const int lane = t & 63;
    const int wid  = t >> 6;
    const int wm   = (wid >> 1) * 64;
    const int wn   = (wid & 1) * 64;
    const int c    = lane & 15;
    const int qq   = lane >> 4;
    const int tr = t >> 1;            // staging row 0..127
    const int kh = (t & 1) * 16;      // staging k-half 0/16

    const float*          Af32 = (const float*)Ap;
    const unsigned short* Af16 = (const unsigned short*)Ap;

    f32x4 acc[4][4];
#pragma unroll
    for (int i = 0; i < 4; ++i)
#pragma unroll
        for (int j = 0; j < 4; ++j)
            acc[i][j] = (f32x4){0.f, 0.f, 0.f, 0.f};

    float4    fa0, fa1, fa2, fa3;     // A stage (fp32 path)
    ushort8_t ua0, ua1;               // A stage (fp16 path)
    ushort8_t ub0, ub1;               // B stage

    auto load_stage = [&](int k0) {
        if constexpr (A_FP32) {
            const float4* Af = reinterpret_cast<const float4*>(
                Af32 + (size_t)(bm + tr) * 256 + k0 + kh);
            fa0 = Af[0]; fa1 = Af[1]; fa2 = Af[2]; fa3 = Af[3];
        } else {
            const ushort8_t* Ab = reinterpret_cast<const ushort8_t*>(
                Af16 + (size_t)(bm + tr) * 256 + k0 + kh);
            ua0 = Ab[0]; ua1 = Ab[1];
        }
        const ushort8_t* Bb = reinterpret_cast<const ushort8_t*>(
            Bt + (size_t)(bn + tr) * 256 + k0 + kh);
        ub0 = Bb[0]; ub1 = Bb[1];
    };

    auto store_stage = [&]() {
        if constexpr (A_FP32) {
            ushort8_t u0, u1;
            u0[0]=f2h(fa0.x); u0[1]=f2h(fa0.y); u0[2]=f2h(fa0.z); u0[3]=f2h(fa0.w);
            u0[4]=f2h(fa1.x); u0[5]=f2h(fa1.y); u0[6]=f2h(fa1.z); u0[7]=f2h(fa1.w);
            u1[0]=f2h(fa2.x); u1[1]=f2h(fa2.y); u1[2]=f2h(fa2.z); u1[3]=f2h(fa2.w);
            u1[4]=f2h(fa3.x); u1[5]=f2h(fa3.y); u1[6]=f2h(fa3.z); u1[7]=f2h(fa3.w);
            *reinterpret_cast<ushort8_t*>(&As[tr * LDT + kh])     = u0;
            *reinterpret_cast<ushort8_t*>(&As[tr * LDT + kh + 8]) = u1;
        } else {
            *reinterpret_cast<ushort8_t*>(&As[tr * LDT + kh])     = ua0;
            *reinterpret_cast<ushort8_t*>(&As[tr * LDT + kh + 8]) = ua1;
        }
        *reinterpret_cast<ushort8_t*>(&Bs[tr * LDT + kh])     = ub0;
        *reinterpret_cast<ushort8_t*>(&Bs[tr * LDT + kh + 8]) = ub1;
    };

    auto compute = [&]() {
        f16x8 af[4], bfr[4];
#pragma unroll
        for (int i = 0; i < 4; ++i)
            af[i] = *reinterpret_cast<const f16x8*>(
                &As[(wm + i * 16 + c) * LDT + qq * 8]);
#pragma unroll
        for (int j = 0; j < 4; ++j)
            bfr[j] = *reinterpret_cast<const f16x8*>(
                &Bs[(wn + j * 16 + c) * LDT + qq * 8]);
#pragma unroll
        for (int i = 0; i < 4; ++i)
#pragma unroll
            for (int j = 0; j < 4; ++j)
                acc[i][j] = __builtin_amdgcn_mfma_f32_16x16x32_f16(
                    af[i], bfr[j], acc[i][j], 0, 0, 0);
    };

    // prologue
    load_stage(0);
    store_stage();
    __syncthreads();
    // steady state: load k0 while computing k0-32
    for (int k0 = 32; k0 < 256; k0 += 32) {
        load_stage(k0);
        compute();
        __syncthreads();
        store_stage();
        __syncthreads();
    }
    compute();

    // ---- epilogue ----
#pragma unroll
    for (int j = 0; j < 4; ++j) {
        const int col    = bn + wn + j * 16 + c;
        const bool second = col >= split;
        const int ccol   = second ? col - split : col;
        const float bv   = second ? bias1[ccol] : bias0[ccol];
#pragma unroll
        for (int i = 0; i < 4; ++i) {
#pragma unroll
            for (int r = 0; r < 4; ++r) {
                const int row = bm + wm + i * 16 + qq * 4 + r;
                const float v0 = acc[i][j][r] + bv;
                if (F16_OUT) {
                    const float v1 = __shfl_xor(v0, 1);
                    if ((lane & 1) == 0) {
                        const unsigned int packed =
                            (unsigned int)f2h(v0) | ((unsigned int)f2h(v1) << 16);
                        unsigned short* Cb = (unsigned short*)(second ? C1 : C0);
                        const int cs = second ? cs1 : cs0;
                        *reinterpret_cast<unsigned int*>(
                            Cb + (size_t)row * cs + ccol) = packed;
                    }
                } else {
                    float* Cf = (float*)C0;
                    Cf[(size_t)row * cs0 + col] = v0;
                }
            }
        }
    }
}

// ---------------------------------------------------------------------------
// Fused front GEMM: [v | off | attn] = q(fp32) @ bigBt^T + fbias, N=640.
//   Same 2-phase prefetch core; 3-way split epilogue.
// ---------------------------------------------------------------------------
__global__ __launch_bounds__(256) void gemm_front(
    const float* __restrict__ Ap, const unsigned short* __restrict__ Bt,
    const float* __restrict__ fbias,
    unsigned short* __restrict__ v16, unsigned short* __restrict__ off16,
    unsigned short* __restrict__ at16)
{
    __shared__ unsigned short As[128 * LDT];
    __shared__ unsigned short Bs[128 * LDT];

    int bxi, byi;
    xcd_tile(bxi, byi);
    const int bm = byi * 128;
    const int bn = bxi * 128;
    const int t    = threadIdx.x;
    const int lane = t & 63;
    const int wid  = t >> 6;
    const int wm   = (wid >> 1) * 64;
    const int wn   = (wid & 1) * 64;
    const int c    = lane & 15;
    const int qq   = lane >> 4;
    const int tr = t >> 1;
    const int kh = (t & 1) * 16;

    f32x4 acc[4][4];
#pragma unroll
    for (int i = 0; i < 4; ++i)
#pragma unroll
        for (int j = 0; j < 4; ++j)
            acc[i][j] = (f32x4){0.f, 0.f, 0.f, 0.f};

    float4    fa0, fa1, fa2, fa3;
    ushort8_t ub0, ub1;

    auto load_stage = [&](int k0) {
        const float4* Af = reinterpret_cast<const float4*>(
            Ap + (size_t)(bm + tr) * 256 + k0 + kh);
        fa0 = Af[0]; fa1 = Af[1]; fa2 = Af[2]; fa3 = Af[3];
        const ushort8_t* Bb = reinterpret_cast<const ushort8_t*>(
            Bt + (size_t)(bn + tr) * 256 + k0 + kh);
        ub0 = Bb[0]; ub1 = Bb[1];
    };

    auto store_stage = [&]() {
        ushort8_t u0, u1;
        u0[0]=f2h(fa0.x); u0[1]=f2h(fa0.y); u0[2]=f2h(fa0.z); u0[3]=f2h(fa0.w);
        u0[4]=f2h(fa1.x); u0[5]=f2h(fa1.y); u0[6]=f2h(fa1.z); u0[7]=f2h(fa1.w);
        u1[0]=f2h(fa2.x); u1[1]=f2h(fa2.y); u1[2]=f2h(fa2.z); u1[3]=f2h(fa2.w);
        u1[4]=f2h(fa3.x); u1[5]=f2h(fa3.y); u1[6]=f2h(fa3.z); u1[7]=f2h(fa3.w);
        *reinterpret_cast<ushort8_t*>(&As[tr * LDT + kh])     = u0;
        *reinterpret_cast<ushort8_t*>(&As[tr * LDT + kh + 8]) = u1;
        *reinterpret_cast<ushort8_t*>(&Bs[tr * LDT + kh])     = ub0;
        *reinterpret_cast<ushort8_t*>(&Bs[tr * LDT + kh + 8]) = ub1;
    };

    auto compute = [&]() {
        f16x8 af[4], bfr[4];
#pragma unroll
        for (int i = 0; i < 4; ++i)
            af[i] = *reinterpret_cast<const f16x8*>(
                &As[(wm + i * 16 + c) * LDT + qq * 8]);
#pragma unroll
        for (int j = 0; j < 4; ++j)
            bfr[j] = *reinterpret_cast<const f16x8*>(
                &Bs[(wn + j * 16 + c) * LDT + qq * 8]);
#pragma unroll
        for (int i = 0; i < 4; ++i)
#pragma unroll
            for (int j = 0; j < 4; ++j)
                acc[i][j] = __builtin_amdgcn_mfma_f32_16x16x32_f16(
                    af[i], bfr[j], acc[i][j], 0, 0, 0);
    };

    load_stage(0);
    store_stage();
    __syncthreads();
    for (int k0 = 32; k0 < 256; k0 += 32) {
        load_stage(k0);
        compute();
        __syncthreads();
        store_stage();
        __syncthreads();
    }
    compute();

#pragma unroll
    for (int j = 0; j < 4; ++j) {
        const int col  = bn + wn + j * 16 + c;      // 0..639
        const float bv = fbias[col];
#pragma unroll
        for (int i = 0; i < 4; ++i) {
#pragma unroll
            for (int r = 0; r < 4; ++r) {
                const int row = bm + wm + i * 16 + qq * 4 + r;
                const float v0 = acc[i][j][r] + bv;
                const float v1 = __shfl_xor(v0, 1);
                if ((lane & 1) == 0) {
                    const unsigned int packed =
                        (unsigned int)f2h(v0) | ((unsigned int)f2h(v1) << 16);
                    unsigned short* dst;
                    if (col < 256)      dst = v16   + (size_t)row * 256 + col;
                    else if (col < 512) dst = off16 + (size_t)row * 256 + (col - 256);
                    else                dst = at16  + (size_t)row * 128 + (col - 512);
                    *reinterpret_cast<unsigned int*>(dst) = packed;
                }
            }
        }
    }
}

// ---------------------------------------------------------------------------
// Fused sampling: unchanged from round 8.
// ---------------------------------------------------------------------------
__global__ __launch_bounds__(256) void sample_kernel(
    const unsigned short* __restrict__ v16,     // [NB][LQ][256] fp16
    const unsigned short* __restrict__ off16,   // [NB][LQ][256] fp16
    const unsigned short* __restrict__ attn16,  // [NB][LQ][128] fp16
    const float* __restrict__ refpts,           // [NB][LQ][4][2] fp32
    unsigned short* __restrict__ pre16)         // [NB][LQ][256] fp16
{
    const int lane = threadIdx.x & 63;
    const int wv   = threadIdx.x >> 6;
    const int bid  = (blockIdx.x & 7) * 1360 + (blockIdx.x >> 3);
    const int row  = bid * 4 + wv;
    const int n    = row / LQ;

    __shared__ uint4 swi[4][328];   // [wave][h*41 + 2j + (j>>1) + cp]

    const ushort4 o4 = reinterpret_cast<const ushort4*>(off16)[(size_t)row * 64 + lane];
    const unsigned int lg = reinterpret_cast<const unsigned int*>(attn16)[(size_t)row * 64 + lane];
    const float l0 = h2f((unsigned short)(lg & 0xffff));
    const float l1 = h2f((unsigned short)(lg >> 16));

    const int h   = lane >> 3;
    const int k   = lane & 7;
    const int lev = k >> 1;
    const float rx = refpts[(size_t)row * 8 + lev * 2 + 0];
    const float ry = refpts[(size_t)row * 8 + lev * 2 + 1];

    float m = fmaxf(l0, l1);
    m = fmaxf(m, __shfl_xor(m, 1));
    m = fmaxf(m, __shfl_xor(m, 2));
    m = fmaxf(m, __shfl_xor(m, 4));
    const float e0 = __expf(l0 - m);
    const float e1 = __expf(l1 - m);
    float s = e0 + e1;
    s += __shfl_xor(s, 1);
    s += __shfl_xor(s, 2);
    s += __shfl_xor(s, 4);
    const float inv = 1.f / s;

    const int  W     = 64 >> lev;
    const int  start = (lev == 0) ? 0 : (lev == 1) ? 4096 : (lev == 2) ? 5120 : 5376;
    const float rs   = 0.015625f * (float)(1 << lev);

#pragma unroll
    for (int pp = 0; pp < 2; ++pp) {
        const float lx = rx + h2f(pp ? o4.z : o4.x) * rs;
        const float ly = ry + h2f(pp ? o4.w : o4.y) * rs;
        const float wgt = (pp ? e1 : e0) * inv;

        const float x = lx * (float)W - 0.5f;
        const float y = ly * (float)W - 0.5f;
        const float fx = floorf(x), fy = floorf(y);
        const int xi = (int)fx, yi = (int)fy;
        const float wx = x - fx, wy = y - fy;

        const int x0 = min(max(xi, 0), W - 1);
        const int x1 = min(max(xi + 1, 0), W - 1);
        const int y0 = min(max(yi, 0), W - 1);
        const int y1 = min(max(yi + 1, 0), W - 1);
        const float vx0 = (xi >= 0 && xi < W)         ? (1.f - wx) : 0.f;
        const float vx1 = (xi + 1 >= 0 && xi + 1 < W) ? wx         : 0.f;
        const float vy0 = (yi >= 0 && yi < W)         ? (1.f - wy) : 0.f;
        const float vy1 = (yi + 1 >= 0 && yi + 1 < W) ? wy         : 0.f;

        const int hb  = h * 64;
        const unsigned int b00 = (unsigned int)((start + y0 * W + x0) * 512 + hb);
        const unsigned int b01 = (unsigned int)((start + y0 * W + x1) * 512 + hb);
        const unsigned int b10 = (unsigned int)((start + y1 * W + x0) * 512 + hb);
        const unsigned int b11 = (unsigned int)((start + y1 * W + x1) * 512 + hb);

        uint4 c0, c1;
        c0.x = __float_as_uint(wgt * vy0 * vx0);
        c0.y = __float_as_uint(wgt * vy0 * vx1);
        c0.z = b00; c0.w = b01;
        c1.x = __float_as_uint(wgt * vy1 * vx0);
        c1.y = __float_as_uint(wgt * vy1 * vx1);
        c1.z = b10; c1.w = b11;
        const int base = h * 41 + 5 * k + 2 * pp;
        swi[wv][base + 0] = c0;
        swi[wv][base + 1] = c1;
    }
    __syncthreads();

    const int cp = (lane >> 2) & 1;
    const int cg = lane & 3;
    const unsigned int koff = cg * 16;

    const int nu = __builtin_amdgcn_readfirstlane(n);
    const char* vn = reinterpret_cast<const char*>(v16) + (size_t)nu * (LQ * 512);
    const uint4* wib = &swi[wv][h * 41 + cp];

#define OFS(j) (2 * (j) + ((j) >> 1))
#define GLD(o) (*reinterpret_cast<const ushort8_t*>(vn + ((o) + koff)))

    float acc[8];
#pragma unroll
    for (int i = 0; i < 8; ++i) acc[i] = 0.f;

    uint4 wi0 = wib[OFS(0)];
    uint4 wi1 = wib[OFS(1)];
    uint4 wi2 = wib[OFS(2)];
    uint4 wi3 = wi2;
    ushort8_t va0 = GLD(wi0.z), vb0 = GLD(wi0.w);
    ushort8_t va1 = GLD(wi1.z), vb1 = GLD(wi1.w);
    ushort8_t va2 = va1,        vb2 = vb1;

#pragma unroll
    for (int j = 0; j < 16; ++j) {
        if (j <= 13) { va2 = GLD(wi2.z); vb2 = GLD(wi2.w); }
        if (j <= 12) wi3 = wib[OFS(j + 3)];

        const float wa = __uint_as_float(wi0.x);
        const float wb = __uint_as_float(wi0.y);
#pragma unroll
        for (int i = 0; i < 8; ++i)
            acc[i] = fmaf(h2f(va0[i]), wa, acc[i]);
#pragma unroll
        for (int i = 0; i < 8; ++i)
            acc[i] = fmaf(h2f(vb0[i]), wb, acc[i]);

        wi0 = wi1; wi1 = wi2; wi2 = wi3;
        va0 = va1; va1 = va2; vb0 = vb1; vb1 = vb2;
    }
#undef OFS
#undef GLD

#pragma unroll
    for (int i = 0; i < 8; ++i)
        acc[i] += __shfl_xor(acc[i], 4);

    if (cp == 0) {
        ushort8_t st;
#pragma unroll
        for (int i = 0; i < 8; ++i) st[i] = f2h(acc[i]);
        *reinterpret_cast<ushort8_t*>(
            pre16 + (size_t)row * 256 + h * 32 + cg * 8) = st;
    }
}

// ---------------------------------------------------------------------------
extern "C" void kernel_launch(void* const* d_in, const int* in_sizes, int n_in,
                              void* d_out, int out_size, void* d_ws, size_t ws_size,
                              hipStream_t stream)
{
    const float* query   = (const float*)d_in[0];
    const float* refpts  = (const float*)d_in[1];
    const float* W_value = (const float*)d_in[4];
    const float* b_value = (const float*)d_in[5];
    const float* W_off   = (const float*)d_in[6];
    const float* b_off   = (const float*)d_in[7];
    const float* W_attn  = (const float*)d_in[8];
    const float* b_attn  = (const float*)d_in[9];
    const float* W_out   = (const float*)d_in[10];
    const float* b_out   = (const float*)d_in[11];
    float* out = (float*)d_out;

    // Workspace layout (fp16 unless noted)
    unsigned short* ws_v16   = (unsigned short*)d_ws;                  // 43520*256
    unsigned short* ws_off16 = ws_v16   + (size_t)MROWS * 256;         // 43520*256
    unsigned short* ws_at16  = ws_off16 + (size_t)MROWS * 256;         // 43520*128
    unsigned short* ws_pre16 = ws_at16  + (size_t)MROWS * 128;         // 43520*256
    unsigned short* ws_bigBt = ws_pre16 + (size_t)MROWS * 256;         // 640*256
    unsigned short* ws_wv16n = ws_bigBt + 640 * 256;                   // 256*256
    unsigned short* ws_woaT  = ws_wv16n + 65536;                       // 384*256
    unsigned short* ws_woT   = ws_woaT  + 98304;                       // 256*256
    float*          ws_fbias = (float*)(ws_woT + 65536);               // 640 f32
    float*          ws_zb    = ws_fbias + 640;                         // 384 f32

    prep_weights<<<dim3(1152), 256, 0, stream>>>(
        W_value, W_off, W_attn, W_out, ws_bigBt, ws_wv16n, ws_woaT, ws_woT);

    combine_bias<<<dim3(642), 256, 0, stream>>>(
        b_value, W_off, W_attn, b_off, b_attn, ws_fbias, ws_zb);

    // WcT = WoaT @ Wv -> bigBt rows 256..639
    gemm_mfma<false, true><<<dim3(2, 3), 256, 0, stream>>>(
        ws_woaT, ws_wv16n, ws_zb, ws_zb,
        ws_bigBt + 65536, ws_bigBt + 65536, 256, 256, 1 << 30);

    // fused front GEMM: [v|off|attn] = q @ bigBt^T + fbias
    gemm_front<<<dim3(5, 340), 256, 0, stream>>>(
        query, ws_bigBt, ws_fbias, ws_v16, ws_off16, ws_at16);

    // fused softmax + bilinear sampling -> pre16
    sample_kernel<<<dim3(MROWS / 4), 256, 0, stream>>>(
        ws_v16, ws_off16, ws_at16, refpts, ws_pre16);

    // out = pre @ W_out + b_out (fp32)
    gemm_mfma<false, false><<<dim3(2, 340), 256, 0, stream>>>(
        ws_pre16, ws_woT, b_out, b_out, out, out, 256, 256, 1 << 30);
}